// Round 31
// baseline (198.366 us; speedup 1.0000x reference)
//
#include <hip/hip_runtime.h>

#define N_NODES 50000
#define N_EDGES 800000
#define IN_C 128
#define HID_C 256
#define OUT_C 128
#define NBLK 196   // ceil(N_NODES / 256)
#define NPART 8    // dst partitions (= XCDs); width 6250
#define PART_W 6250
#define KB2 32     // chunks per partition pass
#define CHUNK (N_EDGES / KB2)  // 25000 edges
// hist+wconv merged kernel (1024 threads):
#define HW_HIST 256
#define HW_W 16
// scatter+xconv merged kernel (1024 threads):
#define SC_SCAT 256
#define SC_XC 1563

typedef __attribute__((ext_vector_type(8))) short short8v;  // 8 bf16
typedef __attribute__((ext_vector_type(4))) float f32x4;

static __device__ __forceinline__ unsigned short f2bf(float f) {
  unsigned int u = __float_as_uint(f);
  unsigned int r = (u + 0x7fffu + ((u >> 16) & 1u)) >> 16;  // RNE
  return (unsigned short)r;
}
static __device__ __forceinline__ float bf2f(unsigned short h) {
  return __uint_as_float(((unsigned int)h) << 16);
}
static __device__ __forceinline__ unsigned int packBF2(float a, float b) {
  return (unsigned int)f2bf(a) | ((unsigned int)f2bf(b) << 16);
}

// Detect int64 edge_index (little-endian: odd words of first 64 values all 0).
static __device__ __forceinline__ int detect64(const int* __restrict__ ei) {
  int nz = 0;
#pragma unroll
  for (int k = 0; k < 64; ++k) nz |= ei[2 * k + 1];
  return (nz == 0) ? 1 : 0;
}
static __device__ __forceinline__ int load_dst(const int* __restrict__ ei,
                                               int is64, int e) {
  return is64 ? (int)((const uint2*)ei)[N_EDGES + e].x : ei[N_EDGES + e];
}
static __device__ __forceinline__ int load_src(const int* __restrict__ ei,
                                               int is64, int e) {
  return is64 ? (int)((const uint2*)ei)[e].x : ei[e];
}

// Per-node edge accumulation over pre-scaled bf16 rows (CW u32 words/row;
// lane reads word `lane`). 16/8/4/1 unroll, pure adds.
template <int CW>
static __device__ __forceinline__ void gather_row(const int* __restrict__ csr_src,
                                                  int rs, int re,
                                                  const unsigned int* __restrict__ hbf,
                                                  int lane, float& a0, float& a1) {
  int e = rs;
  for (; e + 15 < re; e += 16) {
    int s[16];
    unsigned int r[16];
#pragma unroll
    for (int j = 0; j < 16; ++j) s[j] = csr_src[e + j];
#pragma unroll
    for (int j = 0; j < 16; ++j) r[j] = hbf[(long)s[j] * CW + lane];
#pragma unroll
    for (int j = 0; j < 16; ++j) {
      a0 += bf2f((unsigned short)r[j]);
      a1 += bf2f((unsigned short)(r[j] >> 16));
    }
  }
  for (; e + 7 < re; e += 8) {
    int s[8];
    unsigned int r[8];
#pragma unroll
    for (int j = 0; j < 8; ++j) s[j] = csr_src[e + j];
#pragma unroll
    for (int j = 0; j < 8; ++j) r[j] = hbf[(long)s[j] * CW + lane];
#pragma unroll
    for (int j = 0; j < 8; ++j) {
      a0 += bf2f((unsigned short)r[j]);
      a1 += bf2f((unsigned short)(r[j] >> 16));
    }
  }
  for (; e + 3 < re; e += 4) {
    int s[4];
    unsigned int r[4];
#pragma unroll
    for (int j = 0; j < 4; ++j) s[j] = csr_src[e + j];
#pragma unroll
    for (int j = 0; j < 4; ++j) r[j] = hbf[(long)s[j] * CW + lane];
#pragma unroll
    for (int j = 0; j < 4; ++j) {
      a0 += bf2f((unsigned short)r[j]);
      a1 += bf2f((unsigned short)(r[j] >> 16));
    }
  }
  for (; e < re; ++e) {
    const unsigned int r0 = hbf[(long)csr_src[e] * CW + lane];
    a0 += bf2f((unsigned short)r0);
    a1 += bf2f((unsigned short)(r0 >> 16));
  }
}

// ---------------------------------------------------------------------------
// MERGED hist + W-conversion (zero global atomics).
// ---------------------------------------------------------------------------
__global__ __launch_bounds__(1024) void hist_wconv_k(const int* __restrict__ ei,
                                                     int* __restrict__ H,
                                                     const float* __restrict__ W1,
                                                     unsigned int* __restrict__ w1bf,
                                                     const float* __restrict__ W2,
                                                     unsigned int* __restrict__ w2bf) {
  const int b = blockIdx.x;
  if (b < HW_HIST) {
    const int p = b & 7;
    const int c = b >> 3;
    __shared__ unsigned int hist[PART_W];
    __shared__ int s_is64;
    for (int i = threadIdx.x; i < PART_W; i += 1024) hist[i] = 0;
    if (threadIdx.x == 0) s_is64 = detect64(ei);
    __syncthreads();
    const int is64 = s_is64;
    const int s0 = c * CHUNK;
    for (int i = s0 + threadIdx.x; i < s0 + CHUNK; i += 1024) {
      const int d = load_dst(ei, is64, i);
      if (d / PART_W == p) atomicAdd(&hist[d - p * PART_W], 1u);
    }
    __syncthreads();
    int* Hrow = H + (p * KB2 + c) * PART_W;
    for (int i = threadIdx.x; i < PART_W; i += 1024) Hrow[i] = (int)hist[i];
  } else if (b < HW_HIST + HW_W) {
    const int i = (b - HW_HIST) * 1024 + threadIdx.x;
    const float2 f = *(const float2*)(W1 + (long)i * 2);
    w1bf[i] = packBF2(f.x, f.y);
  } else {
    const int i = (b - HW_HIST - HW_W) * 1024 + threadIdx.x;
    const float2 f = *(const float2*)(W2 + (long)i * 2);
    w2bf[i] = packBF2(f.x, f.y);
  }
}

// ---------------------------------------------------------------------------
// Scans over H; bfinal emits rowstart, dinv, and per-(chunk,bin) bases.
// ---------------------------------------------------------------------------
__global__ __launch_bounds__(256) void bsum_k(const int* __restrict__ H,
                                              int* __restrict__ bsum) {
  const int i = blockIdx.x * 256 + threadIdx.x;
  int v = 0;
  if (i < N_NODES) {
    const int p = i / PART_W, bin = i % PART_W;
    const int* Hp = H + p * KB2 * PART_W + bin;
#pragma unroll
    for (int c = 0; c < KB2; ++c) v += Hp[c * PART_W];
  }
#pragma unroll
  for (int off = 32; off > 0; off >>= 1) v += __shfl_down(v, off, 64);
  __shared__ int ws[4];
  if ((threadIdx.x & 63) == 0) ws[threadIdx.x >> 6] = v;
  __syncthreads();
  if (threadIdx.x == 0) bsum[blockIdx.x] = ws[0] + ws[1] + ws[2] + ws[3];
}

__global__ __launch_bounds__(256) void bscan_k(const int* __restrict__ bsum,
                                               int* __restrict__ boff) {
  __shared__ int s[256];
  const int t = threadIdx.x;
  const int v = (t < NBLK) ? bsum[t] : 0;
  s[t] = v;
  __syncthreads();
  for (int off = 1; off < 256; off <<= 1) {
    const int tmp = (t >= off) ? s[t - off] : 0;
    __syncthreads();
    s[t] += tmp;
    __syncthreads();
  }
  if (t < NBLK) boff[t] = s[t] - v;
}

__global__ __launch_bounds__(256) void bfinal_k(int* __restrict__ H,
                                                const int* __restrict__ boff,
                                                int* __restrict__ rowstart,
                                                float* __restrict__ dinv) {
  __shared__ int s[256];
  const int t = threadIdx.x;
  const int i = blockIdx.x * 256 + t;
  int dtot = 0;
  int p = 0, bin = 0;
  if (i < N_NODES) {
    p = i / PART_W;
    bin = i % PART_W;
    int* Hp = H + p * KB2 * PART_W + bin;
#pragma unroll
    for (int c = 0; c < KB2; ++c) dtot += Hp[c * PART_W];
  }
  s[t] = dtot;
  __syncthreads();
  for (int off = 1; off < 256; off <<= 1) {
    const int tmp = (t >= off) ? s[t - off] : 0;
    __syncthreads();
    s[t] += tmp;
    __syncthreads();
  }
  const int run = boff[blockIdx.x] + s[t] - dtot;
  if (i < N_NODES) {
    rowstart[i] = run;
    dinv[i] = rsqrtf((float)dtot + 1.0f);
    int acc = run;
    int* Hp = H + p * KB2 * PART_W + bin;
#pragma unroll
    for (int c = 0; c < KB2; ++c) {
      const int cnt = Hp[c * PART_W];
      Hp[c * PART_W] = acc;
      acc += cnt;
    }
    if (i == N_NODES - 1) rowstart[N_NODES] = run + dtot;
  }
}

// ---------------------------------------------------------------------------
// MERGED scatter + dinv-scaled x conversion (ei decoded inline).
// ---------------------------------------------------------------------------
__global__ __launch_bounds__(1024) void scatter_xconv_k(
    const int* __restrict__ ei, const int* __restrict__ H,
    int* __restrict__ csr_src, const float* __restrict__ x,
    const float* __restrict__ dinv, unsigned int* __restrict__ xbf) {
  const int b = blockIdx.x;
  if (b < SC_SCAT) {
    const int p = b & 7;
    const int c = b >> 3;
    __shared__ unsigned int hist[PART_W];
    __shared__ int s_is64;
    for (int i = threadIdx.x; i < PART_W; i += 1024) hist[i] = 0;
    if (threadIdx.x == 0) s_is64 = detect64(ei);
    __syncthreads();
    const int is64 = s_is64;
    const int s0 = c * CHUNK;
    const int* Hrow = H + (p * KB2 + c) * PART_W;
    for (int i = s0 + threadIdx.x; i < s0 + CHUNK; i += 1024) {
      const int d = load_dst(ei, is64, i);
      if (d / PART_W == p) {
        const int ld = d - p * PART_W;
        const int lr = (int)atomicAdd(&hist[ld], 1u);
        csr_src[Hrow[ld] + lr] = load_src(ei, is64, i);
      }
    }
  } else {
    const int i = (b - SC_SCAT) * 1024 + threadIdx.x;  // float4 index
    if (i < N_NODES * IN_C / 4) {
      const int v = i >> 5;  // 32 float4 per 128-ch row
      const float dv = dinv[v];
      const float4 f = *(const float4*)(x + (long)i * 4);
      uint2 u = {packBF2(dv * f.x, dv * f.y), packBF2(dv * f.z, dv * f.w)};
      *(uint2*)(xbf + (long)i * 2) = u;
    }
  }
}

// ---------------------------------------------------------------------------
// FUSED gather1 + GEMM1 + GEMM2. Per 64-node block:
//   Phase 0: each wave gathers 16 nodes' aggx = dinv*(sum+self) over the
//            pre-scaled xbf rows, packing bf16 DIRECTLY into LDS xs
//            (bitwise-identical to the old gather1+aggxbf round trip).
//   Phase 1: GEMM1 h1 = relu(aggx@W1^T + b1) -> LDS (bf16).
//   Phase 2: GEMM2 h2 = dinv * (h1@W2^T) -> global bf16.
// Cross-block phase overlap hides MFMA under the random-read phase.
// ---------------------------------------------------------------------------
__global__ __launch_bounds__(256) void gather_gemm_fused_k(
    const int* __restrict__ rowstart, const int* __restrict__ csr_src,
    const float* __restrict__ dinv, const unsigned int* __restrict__ xbf,
    const unsigned int* __restrict__ W1BF, const float* __restrict__ b1,
    const unsigned int* __restrict__ W2BF, unsigned int* __restrict__ outBF) {
  constexpr int KP1 = 68;   // aggx LDS row stride (64 + 4 pad)
  constexpr int HP = 132;   // h1 LDS row stride (128 + 4 pad)
  __shared__ unsigned int xs[64 * KP1];   // 17.4 KB
  __shared__ unsigned int h1s[64 * HP];   // 33.8 KB

  const int tid = threadIdx.x;
  const int w = tid >> 6;
  const int l = tid & 63;
  const long nbase = (long)blockIdx.x * 64;
  const int kg = (l >> 4) * 8;
  const int lr = l & 15;
  const int mq0 = (l >> 4) * 4;

  // ---- Phase 0: gather this block's 64 aggx rows into LDS ----
  for (int nn = 0; nn < 16; ++nn) {
    const int row = w * 16 + nn;
    const long v = nbase + row;
    if (v < N_NODES) {
      const int rs = rowstart[v];
      const int re = rowstart[v + 1];
      const float dv = dinv[v];
      float a0 = 0.0f, a1 = 0.0f;
      gather_row<64>(csr_src, rs, re, xbf, l, a0, a1);
      const unsigned int hv = xbf[v * 64 + l];  // self row (pre-scaled)
      const float o0 = dv * (a0 + bf2f((unsigned short)hv));
      const float o1 = dv * (a1 + bf2f((unsigned short)(hv >> 16)));
      xs[row * KP1 + l] = packBF2(o0, o1);
    } else {
      xs[row * KP1 + l] = 0u;
    }
  }
  __syncthreads();

  // ---- Phase 1: GEMM1, wave w owns m in [w*64, w*64+64), K=128 ----
  {
    const int m0w = w * 64;
    f32x4 acc[4][4];
#pragma unroll
    for (int nt = 0; nt < 4; ++nt)
#pragma unroll
      for (int mt = 0; mt < 4; ++mt) acc[nt][mt] = {0.0f, 0.0f, 0.0f, 0.0f};

#pragma unroll
    for (int ks = 0; ks < 4; ++ks) {
      const int ko = ks * 32 + kg;
      short8v wb[4];
#pragma unroll
      for (int mt = 0; mt < 4; ++mt)
        wb[mt] = *(const short8v*)(W1BF + (long)(m0w + mt * 16 + lr) * (IN_C / 2) +
                                   ko / 2);
#pragma unroll
      for (int nt = 0; nt < 4; ++nt) {
        const short8v xb = *(const short8v*)(xs + (nt * 16 + lr) * KP1 + ko / 2);
#pragma unroll
        for (int mt = 0; mt < 4; ++mt)
          acc[nt][mt] = __builtin_amdgcn_mfma_f32_16x16x32_bf16(wb[mt], xb,
                                                               acc[nt][mt], 0, 0, 0);
      }
    }

#pragma unroll
    for (int nt = 0; nt < 4; ++nt) {
      const int nl = nt * 16 + lr;
#pragma unroll
      for (int mt = 0; mt < 4; ++mt) {
        const int mq = m0w + mt * 16 + mq0;
        const float4 bv = *(const float4*)(b1 + mq);
        const float v0 = fmaxf(acc[nt][mt][0] + bv.x, 0.0f);
        const float v1 = fmaxf(acc[nt][mt][1] + bv.y, 0.0f);
        const float v2 = fmaxf(acc[nt][mt][2] + bv.z, 0.0f);
        const float v3 = fmaxf(acc[nt][mt][3] + bv.w, 0.0f);
        uint2 o = {packBF2(v0, v1), packBF2(v2, v3)};
        *(uint2*)(h1s + nl * HP + mq / 2) = o;
      }
    }
  }
  __syncthreads();

  // ---- Phase 2: GEMM2, wave w owns m in [w*32, w*32+32), K=256 ----
  {
    const int m0w = w * 32;
    f32x4 acc[4][2];
#pragma unroll
    for (int nt = 0; nt < 4; ++nt)
#pragma unroll
      for (int mt = 0; mt < 2; ++mt) acc[nt][mt] = {0.0f, 0.0f, 0.0f, 0.0f};

#pragma unroll
    for (int ks = 0; ks < 8; ++ks) {
      const int ko = ks * 32 + kg;
      short8v wb[2];
#pragma unroll
      for (int mt = 0; mt < 2; ++mt)
        wb[mt] = *(const short8v*)(W2BF + (long)(m0w + mt * 16 + lr) * (HID_C / 2) +
                                   ko / 2);
#pragma unroll
      for (int nt = 0; nt < 4; ++nt) {
        const short8v xb = *(const short8v*)(h1s + (nt * 16 + lr) * HP + ko / 2);
#pragma unroll
        for (int mt = 0; mt < 2; ++mt)
          acc[nt][mt] = __builtin_amdgcn_mfma_f32_16x16x32_bf16(wb[mt], xb,
                                                               acc[nt][mt], 0, 0, 0);
      }
    }

    // Epilogue: dinv[n]-scaled packed bf16 h2 to global
#pragma unroll
    for (int nt = 0; nt < 4; ++nt) {
      const long n = nbase + nt * 16 + lr;
      if (n < N_NODES) {
        const float dvn = dinv[n];
#pragma unroll
        for (int mt = 0; mt < 2; ++mt) {
          const int mq = m0w + mt * 16 + mq0;
          uint2 o = {packBF2(dvn * acc[nt][mt][0], dvn * acc[nt][mt][1]),
                     packBF2(dvn * acc[nt][mt][2], dvn * acc[nt][mt][3])};
          *(uint2*)(outBF + n * (OUT_C / 2) + mq / 2) = o;
        }
      }
    }
  }
}

// ---------------------------------------------------------------------------
// Layer-2 gather over pre-scaled h2 rows -> final fp32 output (+bias).
// ---------------------------------------------------------------------------
__global__ __launch_bounds__(256) void gather_out_k(const int* __restrict__ rowstart,
                                                    const int* __restrict__ csr_src,
                                                    const float* __restrict__ dinv,
                                                    const unsigned int* __restrict__ hbf,
                                                    const float* __restrict__ bias,
                                                    float* __restrict__ out) {
  const int v = (blockIdx.x * 256 + threadIdx.x) >> 6;
  if (v >= N_NODES) return;
  const int lane = threadIdx.x & 63;
  const int rs = rowstart[v];
  const int re = rowstart[v + 1];
  const float dv = dinv[v];

  float a0 = 0.0f, a1 = 0.0f;
  gather_row<64>(csr_src, rs, re, hbf, lane, a0, a1);

  const unsigned int hv = hbf[(long)v * 64 + lane];
  float o0 = dv * (a0 + bf2f((unsigned short)hv));
  float o1 = dv * (a1 + bf2f((unsigned short)(hv >> 16)));
  const float2 bv = *(const float2*)(bias + lane * 2);
  o0 += bv.x;
  o1 += bv.y;
  const float2 o = {o0, o1};
  *(float2*)(out + (long)v * 128 + lane * 2) = o;
}

// ---------------------------------------------------------------------------
extern "C" void kernel_launch(void* const* d_in, const int* in_sizes, int n_in,
                              void* d_out, int out_size, void* d_ws, size_t ws_size,
                              hipStream_t stream) {
  (void)in_sizes; (void)n_in; (void)out_size; (void)ws_size;

  const float* x  = (const float*)d_in[0];
  const int*   ei = (const int*)d_in[1];
  const float* W1 = (const float*)d_in[2];
  const float* b1 = (const float*)d_in[3];
  const float* W2 = (const float*)d_in[4];
  const float* b2 = (const float*)d_in[5];
  float* out = (float*)d_out;

  // Workspace layout (bytes):
  char* ws = (char*)d_ws;
  int*   csr_src  = (int*)(ws + 3200000);      //  3.2 MB
  int*   H        = (int*)(ws + 6400000);      //  6.4 MB (8 x 32 x 6250)
  int*   rowstart = (int*)(ws + 12800000);     //  0.2 MB (N+1)
  float* dinv     = (float*)(ws + 13000512);   //  0.2 MB
  int*   bsum     = (int*)(ws + 13200512);
  int*   boff     = (int*)(ws + 13201536);
  unsigned int* w1bf = (unsigned int*)(ws + 13300000);  // 65.5 KB
  unsigned int* w2bf = (unsigned int*)(ws + 13400000);  // 65.5 KB
  unsigned int* h2bf = (unsigned int*)(ws + 27000000);  // 12.8 MB (dinv-scaled)
  unsigned int* xbf  = (unsigned int*)(ws + 91200000);  // 12.8 MB (dinv-scaled)

  const int GB = (N_NODES + 3) / 4;  // gather: 1 node/wave

  // ---- Preproc: zero-atomic CSR build; dinv-scaled x conversion ----
  hist_wconv_k<<<HW_HIST + 2 * HW_W, 1024, 0, stream>>>(ei, H, W1, w1bf, W2,
                                                        w2bf);
  bsum_k<<<NBLK, 256, 0, stream>>>(H, bsum);
  bscan_k<<<1, 256, 0, stream>>>(bsum, boff);
  bfinal_k<<<NBLK, 256, 0, stream>>>(H, boff, rowstart, dinv);
  scatter_xconv_k<<<SC_SCAT + SC_XC, 1024, 0, stream>>>(ei, H, csr_src, x,
                                                        dinv, xbf);

  // ---- Fused gather1 + GEMM1 + GEMM2 (aggx lives only in LDS) ----
  gather_gemm_fused_k<<<(N_NODES + 63) / 64, 256, 0, stream>>>(
      rowstart, csr_src, dinv, xbf, w1bf, b1, w2bf, h2bf);

  // ---- Layer-2 gather: out = b2 + dinv*(sum + self) over pre-scaled h2 ----
  gather_out_k<<<GB, 256, 0, stream>>>(rowstart, csr_src, dinv, h2bf, b2, out);
}

// Round 32
// 148.382 us; speedup vs baseline: 1.3369x; 1.3369x over previous
//
#include <hip/hip_runtime.h>

#define N_NODES 50000
#define N_EDGES 800000
#define IN_C 128
#define HID_C 256
#define OUT_C 128
#define NBLK 196   // ceil(N_NODES / 256)
#define NPART 8    // dst partitions (= XCDs); width 6250
#define PART_W 6250
#define KB2 32     // chunks per partition pass
#define CHUNK (N_EDGES / KB2)  // 25000 edges
#define EB 3125    // edge blocks (convert)
// scatter+conv merged kernel (1024 threads):
#define SC_SCAT 256                  // scatter blocks
#define SC_XC 1563                   // ceil(1600000 / 1024) x-float4 blocks

typedef __attribute__((ext_vector_type(8))) short short8v;  // 8 bf16
typedef __attribute__((ext_vector_type(4))) float f32x4;

static __device__ __forceinline__ unsigned short f2bf(float f) {
  unsigned int u = __float_as_uint(f);
  unsigned int r = (u + 0x7fffu + ((u >> 16) & 1u)) >> 16;  // RNE
  return (unsigned short)r;
}
static __device__ __forceinline__ float bf2f(unsigned short h) {
  return __uint_as_float(((unsigned int)h) << 16);
}
static __device__ __forceinline__ unsigned int packBF2(float a, float b) {
  return (unsigned int)f2bf(a) | ((unsigned int)f2bf(b) << 16);
}

// ---------------------------------------------------------------------------
// Edge conversion (streaming, no atomics): edata[e] = d | s<<16.
// Blocks [EB, EB+128): W1/W2 -> bf16 pairs (no dinv dependency).
// ---------------------------------------------------------------------------
__global__ __launch_bounds__(256) void convert_k(const int* __restrict__ ei,
                                                 unsigned int* __restrict__ edata,
                                                 const float* __restrict__ W1,
                                                 unsigned int* __restrict__ w1bf,
                                                 const float* __restrict__ W2,
                                                 unsigned int* __restrict__ w2bf) {
  const int b = blockIdx.x;
  if (b < EB) {
    __shared__ int s_is64;
    if (threadIdx.x == 0) {
      int nz = 0;
#pragma unroll
      for (int k = 0; k < 64; ++k) nz |= ei[2 * k + 1];
      s_is64 = (nz == 0) ? 1 : 0;
    }
    __syncthreads();
    const int is64 = s_is64;
    const int e = b * 256 + threadIdx.x;
    if (e < N_EDGES) {
      int s, d;
      if (is64) {
        const uint2 sv = ((const uint2*)ei)[e];            // low word = src
        const uint2 dv = ((const uint2*)ei)[N_EDGES + e];  // low word = dst
        s = (int)sv.x;
        d = (int)dv.x;
      } else {
        s = ei[e];
        d = ei[N_EDGES + e];
      }
      edata[e] = (unsigned int)d | ((unsigned int)s << 16);
    }
  } else if (b < EB + 64) {
    const int i = (b - EB) * 256 + threadIdx.x;  // u32 index
    const float2 f = *(const float2*)(W1 + (long)i * 2);
    w1bf[i] = packBF2(f.x, f.y);
  } else {
    const int i = (b - EB - 64) * 256 + threadIdx.x;
    const float2 f = *(const float2*)(W2 + (long)i * 2);
    w2bf[i] = packBF2(f.x, f.y);
  }
}

// ---------------------------------------------------------------------------
// Per-(partition,chunk) LDS histogram (zero global atomics).
// ---------------------------------------------------------------------------
__global__ __launch_bounds__(1024) void hist_k(const unsigned int* __restrict__ edata,
                                               int* __restrict__ H) {
  const int p = blockIdx.x & 7;
  const int c = blockIdx.x >> 3;
  __shared__ unsigned int hist[PART_W];
  for (int i = threadIdx.x; i < PART_W; i += 1024) hist[i] = 0;
  __syncthreads();
  const int s0 = c * CHUNK;
  for (int i = s0 + threadIdx.x; i < s0 + CHUNK; i += 1024) {
    const unsigned int u = edata[i];
    const int d = (int)(u & 0xffffu);
    if (d / PART_W == p) atomicAdd(&hist[d - p * PART_W], 1u);
  }
  __syncthreads();
  int* Hrow = H + (p * KB2 + c) * PART_W;
  for (int i = threadIdx.x; i < PART_W; i += 1024) Hrow[i] = (int)hist[i];
}

// ---------------------------------------------------------------------------
// Scans over H; bfinal emits rowstart, dinv, and per-(chunk,bin) bases.
// ---------------------------------------------------------------------------
__global__ __launch_bounds__(256) void bsum_k(const int* __restrict__ H,
                                              int* __restrict__ bsum) {
  const int i = blockIdx.x * 256 + threadIdx.x;
  int v = 0;
  if (i < N_NODES) {
    const int p = i / PART_W, bin = i % PART_W;
    const int* Hp = H + p * KB2 * PART_W + bin;
#pragma unroll
    for (int c = 0; c < KB2; ++c) v += Hp[c * PART_W];
  }
#pragma unroll
  for (int off = 32; off > 0; off >>= 1) v += __shfl_down(v, off, 64);
  __shared__ int ws[4];
  if ((threadIdx.x & 63) == 0) ws[threadIdx.x >> 6] = v;
  __syncthreads();
  if (threadIdx.x == 0) bsum[blockIdx.x] = ws[0] + ws[1] + ws[2] + ws[3];
}

__global__ __launch_bounds__(256) void bscan_k(const int* __restrict__ bsum,
                                               int* __restrict__ boff) {
  __shared__ int s[256];
  const int t = threadIdx.x;
  const int v = (t < NBLK) ? bsum[t] : 0;
  s[t] = v;
  __syncthreads();
  for (int off = 1; off < 256; off <<= 1) {
    const int tmp = (t >= off) ? s[t - off] : 0;
    __syncthreads();
    s[t] += tmp;
    __syncthreads();
  }
  if (t < NBLK) boff[t] = s[t] - v;
}

__global__ __launch_bounds__(256) void bfinal_k(int* __restrict__ H,
                                                const int* __restrict__ boff,
                                                int* __restrict__ rowstart,
                                                float* __restrict__ dinv) {
  __shared__ int s[256];
  const int t = threadIdx.x;
  const int i = blockIdx.x * 256 + t;
  int dtot = 0;
  int p = 0, bin = 0;
  if (i < N_NODES) {
    p = i / PART_W;
    bin = i % PART_W;
    int* Hp = H + p * KB2 * PART_W + bin;
#pragma unroll
    for (int c = 0; c < KB2; ++c) dtot += Hp[c * PART_W];
  }
  s[t] = dtot;
  __syncthreads();
  for (int off = 1; off < 256; off <<= 1) {
    const int tmp = (t >= off) ? s[t - off] : 0;
    __syncthreads();
    s[t] += tmp;
    __syncthreads();
  }
  const int run = boff[blockIdx.x] + s[t] - dtot;
  if (i < N_NODES) {
    rowstart[i] = run;
    dinv[i] = rsqrtf((float)dtot + 1.0f);
    int acc = run;
    int* Hp = H + p * KB2 * PART_W + bin;
#pragma unroll
    for (int c = 0; c < KB2; ++c) {
      const int cnt = Hp[c * PART_W];
      Hp[c * PART_W] = acc;
      acc += cnt;
    }
    if (i == N_NODES - 1) rowstart[N_NODES] = run + dtot;
  }
}

// ---------------------------------------------------------------------------
// MERGED scatter + dinv-scaled x conversion (needs dinv; runs after bfinal).
// Blocks [0,256): CSR scatter (p=bx&7, per-XCD dst-ranges).
// Blocks [256, 256+SC_XC): xbf[v][c] = bf16(dinv[v]*x[v][c]) (float4-wise).
// ---------------------------------------------------------------------------
__global__ __launch_bounds__(1024) void scatter_xconv_k(
    const unsigned int* __restrict__ edata, const int* __restrict__ H,
    int* __restrict__ csr_src, const float* __restrict__ x,
    const float* __restrict__ dinv, unsigned int* __restrict__ xbf) {
  const int b = blockIdx.x;
  if (b < SC_SCAT) {
    const int p = b & 7;
    const int c = b >> 3;
    __shared__ unsigned int hist[PART_W];
    for (int i = threadIdx.x; i < PART_W; i += 1024) hist[i] = 0;
    __syncthreads();
    const int s0 = c * CHUNK;
    const int* Hrow = H + (p * KB2 + c) * PART_W;
    for (int i = s0 + threadIdx.x; i < s0 + CHUNK; i += 1024) {
      const unsigned int u = edata[i];
      const int d = (int)(u & 0xffffu);
      if (d / PART_W == p) {
        const int ld = d - p * PART_W;
        const int lr = (int)atomicAdd(&hist[ld], 1u);
        csr_src[Hrow[ld] + lr] = (int)(u >> 16);
      }
    }
  } else {
    const int i = (b - SC_SCAT) * 1024 + threadIdx.x;  // float4 index
    if (i < N_NODES * IN_C / 4) {
      const int v = i >> 5;  // 32 float4 per 128-ch row
      const float dv = dinv[v];
      const float4 f = *(const float4*)(x + (long)i * 4);
      uint2 u = {packBF2(dv * f.x, dv * f.y), packBF2(dv * f.z, dv * f.w)};
      *(uint2*)(xbf + (long)i * 2) = u;
    }
  }
}

// ---------------------------------------------------------------------------
// FUSED both-layer GEMM, NT=64, W bf16. GEMM2 epilogue pre-scales h2 rows by
// dinv[n] (so gather2's per-edge term is a pure add).
// ---------------------------------------------------------------------------
__global__ __launch_bounds__(256) void gemm_fused_k(
    const unsigned int* __restrict__ X,     // aggx bf16-packed [N][64]
    const unsigned int* __restrict__ W1BF,  // [256][64] bf16-pairs
    const float* __restrict__ b1,
    const unsigned int* __restrict__ W2BF,  // [128][128] bf16-pairs
    const float* __restrict__ dinv,
    unsigned int* __restrict__ outBF) {     // dinv-scaled h2 bf16 [N][64]
  constexpr int KP1 = 68;   // aggx LDS row stride (64 + 4 pad)
  constexpr int HP = 132;   // h1 LDS row stride (128 + 4 pad)
  __shared__ unsigned int xs[64 * KP1];   // 17.4 KB
  __shared__ unsigned int h1s[64 * HP];   // 33.8 KB

  const int tid = threadIdx.x;
  const int w = tid >> 6;
  const int l = tid & 63;
  const long nbase = (long)blockIdx.x * 64;
  const int kg = (l >> 4) * 8;
  const int lr = l & 15;
  const int mq0 = (l >> 4) * 4;

  // ---- Stage aggx tile ----
#pragma unroll
  for (int i = 0; i < 4; ++i) {
    const int idx = (tid + i * 256) * 4;
    const int row = idx >> 6, col = idx & 63;
    long gr = nbase + row;
    if (gr > N_NODES - 1) gr = N_NODES - 1;
    const uint4 v = *(const uint4*)(X + gr * 64 + col);
    *(uint4*)(xs + row * KP1 + col) = v;
  }
  __syncthreads();

  // ---- GEMM1: wave w owns m in [w*64, w*64+64), K=128 ----
  {
    const int m0w = w * 64;
    f32x4 acc[4][4];
#pragma unroll
    for (int nt = 0; nt < 4; ++nt)
#pragma unroll
      for (int mt = 0; mt < 4; ++mt) acc[nt][mt] = {0.0f, 0.0f, 0.0f, 0.0f};

#pragma unroll
    for (int ks = 0; ks < 4; ++ks) {
      const int ko = ks * 32 + kg;
      short8v wb[4];
#pragma unroll
      for (int mt = 0; mt < 4; ++mt)
        wb[mt] = *(const short8v*)(W1BF + (long)(m0w + mt * 16 + lr) * (IN_C / 2) +
                                   ko / 2);
#pragma unroll
      for (int nt = 0; nt < 4; ++nt) {
        const short8v xb = *(const short8v*)(xs + (nt * 16 + lr) * KP1 + ko / 2);
#pragma unroll
        for (int mt = 0; mt < 4; ++mt)
          acc[nt][mt] = __builtin_amdgcn_mfma_f32_16x16x32_bf16(wb[mt], xb,
                                                               acc[nt][mt], 0, 0, 0);
      }
    }

#pragma unroll
    for (int nt = 0; nt < 4; ++nt) {
      const int nl = nt * 16 + lr;
#pragma unroll
      for (int mt = 0; mt < 4; ++mt) {
        const int mq = m0w + mt * 16 + mq0;
        const float4 bv = *(const float4*)(b1 + mq);
        const float v0 = fmaxf(acc[nt][mt][0] + bv.x, 0.0f);
        const float v1 = fmaxf(acc[nt][mt][1] + bv.y, 0.0f);
        const float v2 = fmaxf(acc[nt][mt][2] + bv.z, 0.0f);
        const float v3 = fmaxf(acc[nt][mt][3] + bv.w, 0.0f);
        uint2 o = {packBF2(v0, v1), packBF2(v2, v3)};
        *(uint2*)(h1s + nl * HP + mq / 2) = o;
      }
    }
  }
  __syncthreads();

  // ---- GEMM2: wave w owns m in [w*32, w*32+32), K=256 from LDS h1s ----
  {
    const int m0w = w * 32;
    f32x4 acc[4][2];
#pragma unroll
    for (int nt = 0; nt < 4; ++nt)
#pragma unroll
      for (int mt = 0; mt < 2; ++mt) acc[nt][mt] = {0.0f, 0.0f, 0.0f, 0.0f};

#pragma unroll
    for (int ks = 0; ks < 8; ++ks) {
      const int ko = ks * 32 + kg;
      short8v wb[2];
#pragma unroll
      for (int mt = 0; mt < 2; ++mt)
        wb[mt] = *(const short8v*)(W2BF + (long)(m0w + mt * 16 + lr) * (HID_C / 2) +
                                   ko / 2);
#pragma unroll
      for (int nt = 0; nt < 4; ++nt) {
        const short8v xb = *(const short8v*)(h1s + (nt * 16 + lr) * HP + ko / 2);
#pragma unroll
        for (int mt = 0; mt < 2; ++mt)
          acc[nt][mt] = __builtin_amdgcn_mfma_f32_16x16x32_bf16(wb[mt], xb,
                                                               acc[nt][mt], 0, 0, 0);
      }
    }

    // Epilogue 2: dinv[n]-scaled packed bf16 h2 to global
#pragma unroll
    for (int nt = 0; nt < 4; ++nt) {
      const long n = nbase + nt * 16 + lr;
      if (n < N_NODES) {
        const float dvn = dinv[n];
#pragma unroll
        for (int mt = 0; mt < 2; ++mt) {
          const int mq = m0w + mt * 16 + mq0;
          uint2 o = {packBF2(dvn * acc[nt][mt][0], dvn * acc[nt][mt][1]),
                     packBF2(dvn * acc[nt][mt][2], dvn * acc[nt][mt][3])};
          *(uint2*)(outBF + n * (OUT_C / 2) + mq / 2) = o;
        }
      }
    }
  }
}

// ---------------------------------------------------------------------------
// Gather over PRE-SCALED bf16 rows: single dependent load per edge, pure-add
// accumulation; final out = dinv[v]*(acc + self) (+bias). 16/8/4/1 unroll.
// OUT_BF: pack bf16 (feeds GEMM1). Else fp32 final output.
// ---------------------------------------------------------------------------
template <int C, bool HAS_BIAS, bool OUT_BF>
__global__ __launch_bounds__(256) void gather_k(const int* __restrict__ rowstart,
                                                const int* __restrict__ csr_src,
                                                const float* __restrict__ dinv,
                                                const unsigned int* __restrict__ hbf,
                                                const float* __restrict__ bias,
                                                float* __restrict__ out,
                                                unsigned int* __restrict__ outBF) {
  const int v = (blockIdx.x * 256 + threadIdx.x) >> 6;
  if (v >= N_NODES) return;
  const int lane = threadIdx.x & 63;
  constexpr int CW = C / 2;
  const int rs = rowstart[v];
  const int re = rowstart[v + 1];
  const float dv = dinv[v];

  float a0 = 0.0f, a1 = 0.0f;

  int e = rs;
  for (; e + 15 < re; e += 16) {
    int s[16];
    unsigned int r[16];
#pragma unroll
    for (int j = 0; j < 16; ++j) s[j] = csr_src[e + j];
#pragma unroll
    for (int j = 0; j < 16; ++j) r[j] = hbf[(long)s[j] * CW + lane];
#pragma unroll
    for (int j = 0; j < 16; ++j) {
      a0 += bf2f((unsigned short)r[j]);
      a1 += bf2f((unsigned short)(r[j] >> 16));
    }
  }
  for (; e + 7 < re; e += 8) {
    int s[8];
    unsigned int r[8];
#pragma unroll
    for (int j = 0; j < 8; ++j) s[j] = csr_src[e + j];
#pragma unroll
    for (int j = 0; j < 8; ++j) r[j] = hbf[(long)s[j] * CW + lane];
#pragma unroll
    for (int j = 0; j < 8; ++j) {
      a0 += bf2f((unsigned short)r[j]);
      a1 += bf2f((unsigned short)(r[j] >> 16));
    }
  }
  for (; e + 3 < re; e += 4) {
    int s[4];
    unsigned int r[4];
#pragma unroll
    for (int j = 0; j < 4; ++j) s[j] = csr_src[e + j];
#pragma unroll
    for (int j = 0; j < 4; ++j) r[j] = hbf[(long)s[j] * CW + lane];
#pragma unroll
    for (int j = 0; j < 4; ++j) {
      a0 += bf2f((unsigned short)r[j]);
      a1 += bf2f((unsigned short)(r[j] >> 16));
    }
  }
  for (; e < re; ++e) {
    const unsigned int r0 = hbf[(long)csr_src[e] * CW + lane];
    a0 += bf2f((unsigned short)r0);
    a1 += bf2f((unsigned short)(r0 >> 16));
  }

  const unsigned int hv = hbf[(long)v * CW + lane];
  float o0 = dv * (a0 + bf2f((unsigned short)hv));
  float o1 = dv * (a1 + bf2f((unsigned short)(hv >> 16)));
  if (HAS_BIAS) {
    const float2 bv = *(const float2*)(bias + lane * 2);
    o0 += bv.x;
    o1 += bv.y;
  }
  if (OUT_BF) {
    outBF[(long)v * CW + lane] = packBF2(o0, o1);
  } else {
    const float2 o = {o0, o1};
    *(float2*)(out + (long)v * CW * 2 + lane * 2) = o;
  }
}

// ---------------------------------------------------------------------------
extern "C" void kernel_launch(void* const* d_in, const int* in_sizes, int n_in,
                              void* d_out, int out_size, void* d_ws, size_t ws_size,
                              hipStream_t stream) {
  (void)in_sizes; (void)n_in; (void)out_size; (void)ws_size;

  const float* x  = (const float*)d_in[0];
  const int*   ei = (const int*)d_in[1];
  const float* W1 = (const float*)d_in[2];
  const float* b1 = (const float*)d_in[3];
  const float* W2 = (const float*)d_in[4];
  const float* b2 = (const float*)d_in[5];
  float* out = (float*)d_out;

  // Workspace layout (bytes):
  char* ws = (char*)d_ws;
  unsigned int* edata = (unsigned int*)(ws + 0);          //  3.2 MB (d | s<<16)
  int*   csr_src  = (int*)(ws + 3200000);      //  3.2 MB
  int*   H        = (int*)(ws + 6400000);      //  6.4 MB (8 x 32 x 6250)
  int*   rowstart = (int*)(ws + 12800000);     //  0.2 MB (N+1)
  float* dinv     = (float*)(ws + 13000512);   //  0.2 MB
  int*   bsum     = (int*)(ws + 13200512);
  int*   boff     = (int*)(ws + 13201536);
  unsigned int* w1bf   = (unsigned int*)(ws + 13300000);  // 65.5 KB
  unsigned int* w2bf   = (unsigned int*)(ws + 13400000);  // 65.5 KB
  unsigned int* aggxbf = (unsigned int*)(ws + 14000000);  // 12.8 MB (bf16 packed)
  unsigned int* h2bf   = (unsigned int*)(ws + 27000000);  // 12.8 MB (dinv-scaled)
  unsigned int* xbf    = (unsigned int*)(ws + 91200000);  // 12.8 MB (dinv-scaled)

  const int GB = (N_NODES + 3) / 4;  // gather: 1 node/wave

  // ---- Preproc: zero-atomic CSR build; x-conv (dinv-scaled) after bfinal ----
  convert_k<<<EB + 128, 256, 0, stream>>>(ei, edata, W1, w1bf, W2, w2bf);
  hist_k<<<NPART * KB2, 1024, 0, stream>>>(edata, H);
  bsum_k<<<NBLK, 256, 0, stream>>>(H, bsum);
  bscan_k<<<1, 256, 0, stream>>>(bsum, boff);
  bfinal_k<<<NBLK, 256, 0, stream>>>(H, boff, rowstart, dinv);
  scatter_xconv_k<<<SC_SCAT + SC_XC, 1024, 0, stream>>>(edata, H, csr_src, x,
                                                        dinv, xbf);

  // ---- Layer 1 gather: aggx = dinv*(sum + self) over pre-scaled xbf ----
  gather_k<IN_C, false, true><<<GB, 256, 0, stream>>>(
      rowstart, csr_src, dinv, xbf, nullptr, nullptr, aggxbf);

  // ---- Fused GEMM1+GEMM2 (h2 pre-scaled by dinv in epilogue) ----
  gemm_fused_k<<<(N_NODES + 63) / 64, 256, 0, stream>>>(aggxbf, w1bf, b1, w2bf,
                                                        dinv, h2bf);

  // ---- Layer 2 gather: out = b2 + dinv*(sum + self) over pre-scaled h2 ----
  gather_k<OUT_C, true, false><<<GB, 256, 0, stream>>>(
      rowstart, csr_src, dinv, h2bf, b2, out, nullptr);
}